// Round 2
// baseline (286.631 us; speedup 1.0000x reference)
//
#include <hip/hip_runtime.h>
#include <hip/hip_bf16.h>

#define N_    2048
#define FIN   256
#define FOUT  128
#define ALPHA 0.01f

typedef short bf16x8 __attribute__((ext_vector_type(8)));
typedef float f32x4  __attribute__((ext_vector_type(4)));

static __device__ __forceinline__ unsigned short f2bf(float x) {
    __hip_bfloat16 h = __float2bfloat16(x);
    return *reinterpret_cast<unsigned short*>(&h);
}

// Kernel 1: h = inp @ W (fp32), emit s1 = h.a1, s2 = h.a2 (fp32) and hT (bf16, [b][f][n]).
// hT store goes through an LDS transpose so global stores are coalesced 64B segments.
__global__ __launch_bounds__(256) void k_lin(
    const float* __restrict__ inp, const float* __restrict__ W,
    const float* __restrict__ av, __hip_bfloat16* __restrict__ hT,
    float* __restrict__ s1, float* __restrict__ s2)
{
    __shared__ float in_lds[32 * FIN];   // 32 KB, reused as transpose buffer later
    int g = blockIdx.x;                  // 512 blocks
    int b = g & 7;                       // XCD-affine: batch -> XCD
    int tile = g >> 3;                   // 0..63
    int i0 = tile << 5;                  // 32 rows per block
    int t = threadIdx.x;

    const float4* src = reinterpret_cast<const float4*>(inp + ((size_t)(b * N_ + i0)) * FIN);
    float4* dst = reinterpret_cast<float4*>(in_lds);
#pragma unroll
    for (int c = 0; c < 8; ++c) dst[t + 256 * c] = src[t + 256 * c];
    __syncthreads();

    int fq = t & 31;    // feature quad: f = fq*4 .. fq*4+3
    int rg = t >> 5;    // row group: rows rg*4 .. rg*4+3
    float acc[4][4];
#pragma unroll
    for (int r = 0; r < 4; ++r)
#pragma unroll
        for (int j = 0; j < 4; ++j) acc[r][j] = 0.f;

    const float4* W4 = reinterpret_cast<const float4*>(W);
    for (int k = 0; k < FIN; k += 4) {
        float4 inr[4];
#pragma unroll
        for (int r = 0; r < 4; ++r)
            inr[r] = *reinterpret_cast<const float4*>(&in_lds[(rg * 4 + r) * FIN + k]);
#pragma unroll
        for (int kk = 0; kk < 4; ++kk) {
            float4 w4 = W4[(k + kk) * 32 + fq];
#pragma unroll
            for (int r = 0; r < 4; ++r) {
                float iv = (&inr[r].x)[kk];
                acc[r][0] = fmaf(iv, w4.x, acc[r][0]);
                acc[r][1] = fmaf(iv, w4.y, acc[r][1]);
                acc[r][2] = fmaf(iv, w4.z, acc[r][2]);
                acc[r][3] = fmaf(iv, w4.w, acc[r][3]);
            }
        }
    }

    // s1/s2: reduce h . a1 / a2 across the 32 fq-lanes
    float a1v[4], a2v[4];
#pragma unroll
    for (int j = 0; j < 4; ++j) {
        a1v[j] = av[fq * 4 + j];
        a2v[j] = av[FOUT + fq * 4 + j];
    }
#pragma unroll
    for (int r = 0; r < 4; ++r) {
        float p1 = acc[r][0] * a1v[0] + acc[r][1] * a1v[1] + acc[r][2] * a1v[2] + acc[r][3] * a1v[3];
        float p2 = acc[r][0] * a2v[0] + acc[r][1] * a2v[1] + acc[r][2] * a2v[2] + acc[r][3] * a2v[3];
#pragma unroll
        for (int off = 1; off < 32; off <<= 1) {
            p1 += __shfl_xor(p1, off);
            p2 += __shfl_xor(p2, off);
        }
        if (fq == 0) {
            int row = i0 + rg * 4 + r;
            s1[b * N_ + row] = p1;
            s2[b * N_ + row] = p2;
        }
    }

    // transpose h tile through LDS, then coalesced bf16 stores
    __syncthreads();   // in_lds reads done; safe to reuse
    unsigned short* hb = reinterpret_cast<unsigned short*>(in_lds);   // [128][33]
#pragma unroll
    for (int j = 0; j < 4; ++j)
#pragma unroll
        for (int r = 0; r < 4; ++r)
            hb[(fq * 4 + j) * 33 + rg * 4 + r] = f2bf(acc[r][j]);
    __syncthreads();
    {
        int f = t >> 1;
        int c0 = (t & 1) * 16;
        unsigned short tmp[16];
#pragma unroll
        for (int c = 0; c < 16; ++c) tmp[c] = hb[f * 33 + c0 + c];
        int4* dst4 = reinterpret_cast<int4*>(&hT[((size_t)(b * FOUT + f)) * N_ + i0 + c0]);
        dst4[0] = reinterpret_cast<const int4*>(tmp)[0];
        dst4[1] = reinterpret_cast<const int4*>(tmp)[1];
    }
}

// Tiny kernel: per-batch max of s2 (for the fixed softmax bound)
__global__ __launch_bounds__(256) void k_s2max(const float* __restrict__ s2,
                                               float* __restrict__ s2max)
{
    __shared__ float red[4];
    int b = blockIdx.x, t = threadIdx.x;
    const float4* p = reinterpret_cast<const float4*>(s2 + b * N_);
    float4 v0 = p[t], v1 = p[t + 256];
    float m = fmaxf(fmaxf(fmaxf(v0.x, v0.y), fmaxf(v0.z, v0.w)),
                    fmaxf(fmaxf(v1.x, v1.y), fmaxf(v1.z, v1.w)));
#pragma unroll
    for (int off = 1; off < 64; off <<= 1) m = fmaxf(m, __shfl_xor(m, off));
    if ((t & 63) == 0) red[t >> 6] = m;
    __syncthreads();
    if (t == 0) s2max[b] = fmaxf(fmaxf(red[0], red[1]), fmaxf(red[2], red[3]));
}

// Kernel 2: fused masked-softmax attention + PV (bf16 MFMA) + ReLU.
// Fixed per-row softmax shift m_row = leaky(s1[r] + max_b s2) -- an upper bound on
// every score in the row, so NO online max / rescale / cross-lane ops / barriers
// in the main loop. Merge across the 4 j-chunk waves is a plain sum.
__global__ __launch_bounds__(256, 4) void k_attn(
    const int* __restrict__ adj, const __hip_bfloat16* __restrict__ hT,
    const float* __restrict__ s1g, const float* __restrict__ s2g,
    const float* __restrict__ s2maxg, float* __restrict__ out)
{
    __shared__ float accb[4][16][128];   // 32 KB (store is 4-way-conflict, epilogue only)
    __shared__ float l_s[4][16];

    int g = blockIdx.x;                  // 1024 blocks
    int b = g & 7;                       // XCD-affine: hT[b] stays L2-local
    int tile = g >> 3;
    int i0 = tile << 4;                  // 16 rows
    int t = threadIdx.x;
    int w = t >> 6;
    int l = t & 63;
    int r = l & 15;                      // score row for this lane
    int lg = l >> 4;                     // k-group
    int jc = w * 512;

    const float s1r = s1g[b * N_ + i0 + r];
    float eb = s1r + s2maxg[b];
    const float m_row = fmaxf(eb, ALPHA * eb);   // upper bound on leaky(e) for this row

    const int4* adjp = reinterpret_cast<const int4*>(
        adj + ((size_t)(b * N_ + i0 + r)) * N_ + jc + lg * 8);
    const float4* s2p = reinterpret_cast<const float4*>(s2g + b * N_ + jc + lg * 8);
    const bf16x8* hv = reinterpret_cast<const bf16x8*>(hT);
    size_t h0 = (((size_t)(b * FOUT + r)) * N_ + jc + lg * 8) >> 3;
    const size_t FRAG = (size_t)16 * N_ / 8;     // 16 f-rows ahead, in bf16x8 units

    float l_run = 0.0f;
    f32x4 acc[8];
#pragma unroll
    for (int q = 0; q < 8; ++q) acc[q] = (f32x4){0.f, 0.f, 0.f, 0.f};

    // 1-step explicit prefetch of the only HBM stream (adj) + s2
    int4 aj0 = adjp[0], aj1 = adjp[1];
    float4 s2a = s2p[0], s2b = s2p[1];

    for (int step = 0; step < 16; ++step) {
        int4 c0 = aj0, c1 = aj1;
        float4 ca = s2a, cb = s2b;
        if (step < 15) {
            aj0 = adjp[(step + 1) * 8];
            aj1 = adjp[(step + 1) * 8 + 1];
            s2a = s2p[(step + 1) * 8];
            s2b = s2p[(step + 1) * 8 + 1];
        }
        float sv[8] = {ca.x, ca.y, ca.z, ca.w, cb.x, cb.y, cb.z, cb.w};
        int am[8] = {c0.x, c0.y, c0.z, c0.w, c1.x, c1.y, c1.z, c1.w};

        bf16x8 af;
        float ps = 0.f;
#pragma unroll
        for (int e = 0; e < 8; ++e) {
            float v = s1r + sv[e];
            v = fmaxf(v, ALPHA * v);                       // leaky relu
            float p = (am[e] > 0) ? __expf(v - m_row) : 0.f;
            ps += p;
            af[e] = (short)f2bf(p);
        }
        l_run += ps;

#pragma unroll
        for (int q = 0; q < 8; ++q) {
            bf16x8 bfr = hv[h0 + (size_t)q * FRAG + step * 4];
            acc[q] = __builtin_amdgcn_mfma_f32_16x16x32_bf16(af, bfr, acc[q], 0, 0, 0);
        }
    }

    // row-sum of l across the 4 k-groups; lanes 0..15 hold rows 0..15
    l_run += __shfl_xor(l_run, 16);
    l_run += __shfl_xor(l_run, 32);
    if (l < 16) l_s[w][l] = l_run;

#pragma unroll
    for (int q = 0; q < 8; ++q)
#pragma unroll
        for (int rr = 0; rr < 4; ++rr)
            accb[w][lg * 4 + rr][q * 16 + r] = acc[q][rr];
    __syncthreads();

    int f = t & 127;
    int rh = t >> 7;
#pragma unroll
    for (int rr = 0; rr < 8; ++rr) {
        int row = rh * 8 + rr;
        float L = l_s[0][row] + l_s[1][row] + l_s[2][row] + l_s[3][row];
        float v = accb[0][row][f] + accb[1][row][f] + accb[2][row][f] + accb[3][row][f];
        v = v / L;
        out[((size_t)(b * N_ + i0 + row)) * FOUT + f] = fmaxf(v, 0.f);
    }
}

extern "C" void kernel_launch(void* const* d_in, const int* in_sizes, int n_in,
                              void* d_out, int out_size, void* d_ws, size_t ws_size,
                              hipStream_t stream) {
    (void)in_sizes; (void)n_in; (void)out_size; (void)ws_size;
    const float* inp = (const float*)d_in[0];
    const int*   adj = (const int*)d_in[1];
    const float* W   = (const float*)d_in[2];
    const float* a   = (const float*)d_in[3];
    float* out = (float*)d_out;

    char* ws = (char*)d_ws;
    __hip_bfloat16* hT = (__hip_bfloat16*)ws;                      // 4 MB
    float* s1 = (float*)(ws + (size_t)8 * FOUT * N_ * 2);          // 64 KB
    float* s2 = s1 + 8 * N_;                                       // 64 KB
    float* s2max = s2 + 8 * N_;                                    // 32 B

    k_lin<<<512, 256, 0, stream>>>(inp, W, a, hT, s1, s2);
    k_s2max<<<8, 256, 0, stream>>>(s2, s2max);
    k_attn<<<1024, 256, 0, stream>>>(adj, hT, s1, s2, s2max, out);
}